// Round 3
// baseline (1496.057 us; speedup 1.0000x reference)
//
#include <hip/hip_runtime.h>
#include <math.h>

#define CPT 2                     // output cols per thread
#define RPT 6                     // output rows per thread
#define NCP 16                    // col-pairs per block
#define NTY 16                    // row-groups per block  (NCP*NTY = 256 threads)
#define TILE_X 32                 // output cols per block
#define TILE_Y (RPT * NTY)        // 96 output rows per block
#define IN_X 42                   // staged cols (TILE_X + 10)
#define IN_Y (TILE_Y + 10)        // 106 staged rows
#define HALO 10

// Gaussian window (size 11, sigma 1.5), normalized; computed in double offline.
#define G0 0.00102838f
#define G1 0.00759875f
#define G2 0.03600077f
#define G3 0.10936070f
#define G4 0.21300554f
#define G5 0.26601173f
__device__ __constant__ const float g_w[11] =
    {G0, G1, G2, G3, G4, G5, G4, G3, G2, G1, G0};

// -------------------- fused SSIM-level (+pool) kernel --------------------
// Block: 32x96 output tile of one (b,c) plane. Stage 106x42 of both images
// in LDS; each thread computes a 2-col x 6-row output patch: horizontal
// 11-tap per input row into registers (float2 LDS reads, window shared
// across the column pair), vertical conv scatter-accumulated into 6x2x5
// register accumulators (all indices compile-time), SSIM pointwise, block
// reduce, double atomicAdd. Also emits the 2x2 avg-pooled images.
__global__ __launch_bounds__(256)
void msssim_level_kernel(const float* __restrict__ img1,
                         const float* __restrict__ img2,
                         int H, int level, double* __restrict__ sums,
                         float* __restrict__ pool1, float* __restrict__ pool2)
{
    __shared__ float sA[IN_Y][IN_X];
    __shared__ float sB[IN_Y][IN_X];
    __shared__ float wred[4][2];

    const int tid = threadIdx.x;
    const int Hout = H - HALO;
    const int oy0 = blockIdx.y * TILE_Y;
    const int ox0 = blockIdx.x * TILE_X;
    const long long base = (long long)blockIdx.z * H * H;

    // ---- stage 106x42 input tiles as float2 (even offsets -> 8B aligned)
    for (int w = tid; w < IN_Y * (IN_X / 2); w += 256) {
        const int r = w / (IN_X / 2);
        const int c = 2 * (w % (IN_X / 2));
        const int y = oy0 + r, x = ox0 + c;
        float2 a = make_float2(0.f, 0.f), b = make_float2(0.f, 0.f);
        if (y < H && x < H) {   // H even, x even -> x+1 < H too
            const long long idx = base + (long long)y * H + x;
            a = *(const float2*)(img1 + idx);
            b = *(const float2*)(img2 + idx);
        }
        *(float2*)&sA[r][c] = a;
        *(float2*)&sB[r][c] = b;
    }
    __syncthreads();

    // ---- fused 2x2 avg pool for next level (tile 96x32 -> 48x16)
    if (pool1 != nullptr) {
        const int Hp = H >> 1;
        for (int w = tid; w < (TILE_Y / 2) * (TILE_X / 2); w += 256) {
            const int pr = w / (TILE_X / 2), pc = w % (TILE_X / 2);
            const int py = (oy0 >> 1) + pr, px = (ox0 >> 1) + pc;
            if (py < Hp && px < Hp) {
                const int r = 2 * pr, c = 2 * pc;
                const float a = 0.25f * (sA[r][c] + sA[r][c + 1] + sA[r + 1][c] + sA[r + 1][c + 1]);
                const float b = 0.25f * (sB[r][c] + sB[r][c + 1] + sB[r + 1][c] + sB[r + 1][c + 1]);
                const long long ob = (long long)blockIdx.z * Hp * Hp + (long long)py * Hp + px;
                pool1[ob] = a;
                pool2[ob] = b;
            }
        }
    }

    // ---- horizontal pass per input row (regs) + vertical scatter (regs)
    const int cp = tid & (NCP - 1);        // col-pair index
    const int ty = tid >> 4;               // row-group index
    const int c0 = cp * CPT;               // tile-local first output col
    const int ry0 = ty * RPT;              // tile-local first output row

    float acc[RPT][CPT][5];
    #pragma unroll
    for (int o = 0; o < RPT; ++o)
        #pragma unroll
        for (int cc = 0; cc < CPT; ++cc)
            #pragma unroll
            for (int ch = 0; ch < 5; ++ch) acc[o][cc][ch] = 0.f;

    #pragma unroll
    for (int i = 0; i < RPT + 10; ++i) {
        const int r = ry0 + i;
        // 12 input values per image: 6 aligned float2 LDS reads each
        float xa[12], xb[12];
        #pragma unroll
        for (int j = 0; j < 6; ++j) {
            const float2 a = *(const float2*)&sA[r][c0 + 2 * j];
            const float2 b = *(const float2*)&sB[r][c0 + 2 * j];
            xa[2 * j] = a.x; xa[2 * j + 1] = a.y;
            xb[2 * j] = b.x; xb[2 * j + 1] = b.y;
        }
        float h1[CPT] = {0.f, 0.f}, h2[CPT] = {0.f, 0.f};
        float h11[CPT] = {0.f, 0.f}, h22[CPT] = {0.f, 0.f}, h12[CPT] = {0.f, 0.f};
        #pragma unroll
        for (int j = 0; j < 12; ++j) {
            const float x1 = xa[j], x2 = xb[j];
            const float q11 = x1 * x1, q22 = x2 * x2, q12 = x1 * x2;
            if (j <= 10) {           // contributes to col 0, weight g[j]
                const float wk = g_w[j];
                h1[0]  += wk * x1;  h2[0]  += wk * x2;
                h11[0] += wk * q11; h22[0] += wk * q22; h12[0] += wk * q12;
            }
            if (j >= 1) {            // contributes to col 1, weight g[j-1]
                const float wk = g_w[j - 1];
                h1[1]  += wk * x1;  h2[1]  += wk * x2;
                h11[1] += wk * q11; h22[1] += wk * q22; h12[1] += wk * q12;
            }
        }
        #pragma unroll
        for (int o = 0; o < RPT; ++o) {
            const int kk = i - o;
            if (kk >= 0 && kk <= 10) {   // compile-time resolved
                const float wv = g_w[kk];
                #pragma unroll
                for (int cc = 0; cc < CPT; ++cc) {
                    acc[o][cc][0] += wv * h1[cc];
                    acc[o][cc][1] += wv * h2[cc];
                    acc[o][cc][2] += wv * h11[cc];
                    acc[o][cc][3] += wv * h22[cc];
                    acc[o][cc][4] += wv * h12[cc];
                }
            }
        }
    }

    // ---- SSIM pointwise + per-thread accumulate
    const float C1 = 4.0e-4f;   // (0.01*2)^2
    const float C2 = 3.6e-3f;   // (0.03*2)^2
    float ssim_acc = 0.f, cs_acc = 0.f;
    #pragma unroll
    for (int o = 0; o < RPT; ++o) {
        const int oy = oy0 + ry0 + o;
        #pragma unroll
        for (int cc = 0; cc < CPT; ++cc) {
            const int ox = ox0 + c0 + cc;
            if (oy < Hout && ox < Hout) {
                const float mu1 = acc[o][cc][0];
                const float mu2 = acc[o][cc][1];
                const float mu1s = mu1 * mu1;
                const float mu2s = mu2 * mu2;
                const float mu12 = mu1 * mu2;
                const float s1  = acc[o][cc][2] - mu1s;
                const float s2  = acc[o][cc][3] - mu2s;
                const float s12 = acc[o][cc][4] - mu12;
                const float v1 = 2.f * s12 + C2;
                const float v2 = s1 + s2 + C2;
                cs_acc   += v1 / v2;
                ssim_acc += ((2.f * mu12 + C1) * v1) / ((mu1s + mu2s + C1) * v2);
            }
        }
    }

    // ---- block reduction
    #pragma unroll
    for (int off = 32; off > 0; off >>= 1) {
        ssim_acc += __shfl_down(ssim_acc, off);
        cs_acc   += __shfl_down(cs_acc, off);
    }
    const int wave = tid >> 6;
    if ((tid & 63) == 0) { wred[wave][0] = ssim_acc; wred[wave][1] = cs_acc; }
    __syncthreads();
    if (tid == 0) {
        const float s = wred[0][0] + wred[1][0] + wred[2][0] + wred[3][0];
        const float c = wred[0][1] + wred[1][1] + wred[2][1] + wred[3][1];
        atomicAdd(&sums[level],     (double)s);
        atomicAdd(&sums[5 + level], (double)c);
    }
}

// -------------------- final combine --------------------
__global__ void msssim_final_kernel(const double* __restrict__ sums,
                                    float* __restrict__ out)
{
    if (threadIdx.x == 0 && blockIdx.x == 0) {
        const double W[5] = {0.0448, 0.2856, 0.3001, 0.2363, 0.1333};
        const int Houts[5] = {502, 246, 118, 54, 22};
        double mssim[5], mcs[5];
        for (int l = 0; l < 5; ++l) {
            const double cnt = 48.0 * (double)Houts[l] * (double)Houts[l];
            mssim[l] = (sums[l]     / cnt + 1.0) * 0.5;
            mcs[l]   = (sums[5 + l] / cnt + 1.0) * 0.5;
        }
        const double p2 = pow(mssim[4], W[4]);
        double prod = 1.0;
        for (int l = 0; l < 4; ++l) prod *= pow(mcs[l], W[l]) * p2;
        out[0] = (float)(1.0 - prod);
    }
}

// -------------------- launch --------------------
extern "C" void kernel_launch(void* const* d_in, const int* in_sizes, int n_in,
                              void* d_out, int out_size, void* d_ws, size_t ws_size,
                              hipStream_t stream)
{
    const float* img1 = (const float*)d_in[0];
    const float* img2 = (const float*)d_in[1];
    float* out = (float*)d_out;
    (void)in_sizes; (void)n_in; (void)out_size; (void)ws_size;

    char* ws = (char*)d_ws;
    double* sums = (double*)ws;                      // 10 doubles
    float* X1 = (float*)(ws + 256);                  // 3,145,728 floats
    float* X2 = X1 + 3145728;
    float* Y1 = X2 + 3145728;                        // 786,432 floats
    float* Y2 = Y1 + 786432;

    hipMemsetAsync(sums, 0, 10 * sizeof(double), stream);

    auto launch_level = [&](const float* a, const float* b, int H, int level,
                            float* pa, float* pb) {
        const int Hout = H - HALO;
        const int xt = (Hout + TILE_X - 1) / TILE_X;
        const int yt = (Hout + TILE_Y - 1) / TILE_Y;
        dim3 grid(xt, yt, 48);
        hipLaunchKernelGGL(msssim_level_kernel, grid, dim3(256), 0, stream,
                           a, b, H, level, sums, pa, pb);
    };

    launch_level(img1, img2, 512, 0, X1, X2);      // level 0, pool -> X (256)
    launch_level(X1, X2, 256, 1, Y1, Y2);          // level 1, pool -> Y (128)
    launch_level(Y1, Y2, 128, 2, X1, X2);          // level 2, pool -> X (64)
    launch_level(X1, X2, 64, 3, Y1, Y2);           // level 3, pool -> Y (32)
    launch_level(Y1, Y2, 32, 4, nullptr, nullptr); // level 4

    hipLaunchKernelGGL(msssim_final_kernel, dim3(1), dim3(64), 0, stream, sums, out);
}

// Round 4
// 454.961 us; speedup vs baseline: 3.2883x; 3.2883x over previous
//
#include <hip/hip_runtime.h>
#include <math.h>

#define TILE 32              // output tile (both dims)
#define IN_DIM 42            // staged input tile (TILE + 10)
#define HALO 10
#define HT_STRIDE 44         // padded row length of transposed h-buffers (16B-aligned)
#define RPT 4                // output rows per thread in v-pass

// Gaussian window (size 11, sigma 1.5), normalized.
__device__ __constant__ float g_w[11] = {
    0.00102838f, 0.00759875f, 0.03600077f, 0.10936070f, 0.21300554f,
    0.26601173f, 0.21300554f, 0.10936070f, 0.03600077f, 0.00759875f,
    0.00102838f};

// -------------------- fused SSIM-level (+pool) kernel --------------------
// Block: 32x32 output tile of one (b,c) plane, 256 threads.
//  1. stage 42x42 of both images in LDS (float2)
//  2. fused 2x2 avg-pool of the owned 32x32 input region -> next level
//  3. h-pass: 11-tap horizontal conv, 5 channels, computed per column-PAIR
//     into registers (float2 LDS reads), then written to TRANSPOSED LDS
//     buffers ht[ch][col][row] that ALIAS the staging area (sync between)
//  4. v-pass: per thread (col, 4 rows): contiguous float4 reads from ht,
//     11-tap vertical conv, SSIM pointwise
//  5. block reduce, double atomicAdd into sums[level] / sums[5+level]
__global__ __launch_bounds__(256)
void msssim_level_kernel(const float* __restrict__ img1,
                         const float* __restrict__ img2,
                         int H, int level, double* __restrict__ sums,
                         float* __restrict__ pool1, float* __restrict__ pool2)
{
    __shared__ float smem[5 * TILE * HT_STRIDE];   // 7040 floats = 28160 B (aliased)
    __shared__ float wred[4][2];
    float* sA = smem;                          // [42][42]
    float* sB = smem + IN_DIM * IN_DIM;        // [42][42]

    const int tid = threadIdx.x;
    const int Hout = H - HALO;
    const int oy0 = blockIdx.y * TILE;
    const int ox0 = blockIdx.x * TILE;
    const long long base = (long long)blockIdx.z * H * H;

    // ---- 1. stage 42x42 as float2 (21 pairs per row)
    for (int w = tid; w < IN_DIM * 21; w += 256) {
        const int r = w / 21, c = 2 * (w % 21);
        const int y = oy0 + r, x = ox0 + c;
        float2 a = make_float2(0.f, 0.f), b = make_float2(0.f, 0.f);
        if (y < H && x < H) {      // x even, H even -> x+1 < H too
            const long long idx = base + (long long)y * H + x;
            a = *(const float2*)(img1 + idx);
            b = *(const float2*)(img2 + idx);
        }
        *(float2*)&sA[r * IN_DIM + c] = a;
        *(float2*)&sB[r * IN_DIM + c] = b;
    }
    __syncthreads();

    // ---- 2. fused 2x2 avg pool (owned 32x32 input region -> 16x16)
    if (pool1 != nullptr) {
        const int pr = tid >> 4, pc = tid & 15;
        const int Hp = H >> 1;
        const int py = (oy0 >> 1) + pr, px = (ox0 >> 1) + pc;
        if (py < Hp && px < Hp) {
            const int r = 2 * pr, c = 2 * pc;
            const float2 a0 = *(const float2*)&sA[r * IN_DIM + c];
            const float2 a1 = *(const float2*)&sA[(r + 1) * IN_DIM + c];
            const float2 b0 = *(const float2*)&sB[r * IN_DIM + c];
            const float2 b1 = *(const float2*)&sB[(r + 1) * IN_DIM + c];
            const long long ob = (long long)blockIdx.z * Hp * Hp + (long long)py * Hp + px;
            pool1[ob] = 0.25f * (a0.x + a0.y + a1.x + a1.y);
            pool2[ob] = 0.25f * (b0.x + b0.y + b1.x + b1.y);
        }
    }

    // ---- 3. h-pass: 672 column-pairs (42 rows x 16 pairs), 3 iters/thread
    float hreg[3][10];
    #pragma unroll
    for (int t = 0; t < 3; ++t) {
        const int p = tid + 256 * t;
        if (p < IN_DIM * 16) {
            const int r = p >> 4;
            const int c0 = (p & 15) * 2;
            float xa[12], xb[12];
            #pragma unroll
            for (int j = 0; j < 6; ++j) {
                const float2 a = *(const float2*)&sA[r * IN_DIM + c0 + 2 * j];
                const float2 b = *(const float2*)&sB[r * IN_DIM + c0 + 2 * j];
                xa[2 * j] = a.x; xa[2 * j + 1] = a.y;
                xb[2 * j] = b.x; xb[2 * j + 1] = b.y;
            }
            float h1a = 0.f, h2a = 0.f, h11a = 0.f, h22a = 0.f, h12a = 0.f;
            float h1b = 0.f, h2b = 0.f, h11b = 0.f, h22b = 0.f, h12b = 0.f;
            #pragma unroll
            for (int j = 0; j < 12; ++j) {
                const float x1 = xa[j], x2 = xb[j];
                const float q11 = x1 * x1, q22 = x2 * x2, q12 = x1 * x2;
                if (j <= 10) {             // col c0, weight g[j]
                    const float wk = g_w[j];
                    h1a += wk * x1;  h2a += wk * x2;
                    h11a += wk * q11; h22a += wk * q22; h12a += wk * q12;
                }
                if (j >= 1) {              // col c0+1, weight g[j-1]
                    const float wk = g_w[j - 1];
                    h1b += wk * x1;  h2b += wk * x2;
                    h11b += wk * q11; h22b += wk * q22; h12b += wk * q12;
                }
            }
            hreg[t][0] = h1a;  hreg[t][1] = h1b;
            hreg[t][2] = h2a;  hreg[t][3] = h2b;
            hreg[t][4] = h11a; hreg[t][5] = h11b;
            hreg[t][6] = h22a; hreg[t][7] = h22b;
            hreg[t][8] = h12a; hreg[t][9] = h12b;
        }
    }
    __syncthreads();   // everyone done READING sA/sB before overwriting

    // write transposed: ht[ch][col][row], row-stride 44
    #pragma unroll
    for (int t = 0; t < 3; ++t) {
        const int p = tid + 256 * t;
        if (p < IN_DIM * 16) {
            const int r = p >> 4;
            const int c0 = (p & 15) * 2;
            #pragma unroll
            for (int ch = 0; ch < 5; ++ch) {
                smem[(ch * TILE + c0)     * HT_STRIDE + r] = hreg[t][2 * ch];
                smem[(ch * TILE + c0 + 1) * HT_STRIDE + r] = hreg[t][2 * ch + 1];
            }
        }
    }
    __syncthreads();

    // ---- 4. v-pass: thread = (col tx, rows r0..r0+3)
    const int tx = tid & 31;
    const int rg = tid >> 5;
    const int r0 = rg * RPT;

    float acc[RPT][5];
    #pragma unroll
    for (int ch = 0; ch < 5; ++ch) {
        const float* hb = &smem[(ch * TILE + tx) * HT_STRIDE];
        float f[16];
        #pragma unroll
        for (int k = 0; k < 4; ++k)
            *(float4*)&f[4 * k] = *(const float4*)&hb[r0 + 4 * k];
        #pragma unroll
        for (int o = 0; o < RPT; ++o) {
            float s = 0.f;
            #pragma unroll
            for (int k = 0; k < 11; ++k) s += g_w[k] * f[o + k];
            acc[o][ch] = s;
        }
    }

    // ---- SSIM pointwise
    const float C1 = 4.0e-4f;   // (0.01*2)^2
    const float C2 = 3.6e-3f;   // (0.03*2)^2
    float ssim_acc = 0.f, cs_acc = 0.f;
    #pragma unroll
    for (int o = 0; o < RPT; ++o) {
        const int oy = oy0 + r0 + o;
        const int ox = ox0 + tx;
        if (oy < Hout && ox < Hout) {
            const float mu1 = acc[o][0];
            const float mu2 = acc[o][1];
            const float mu1s = mu1 * mu1;
            const float mu2s = mu2 * mu2;
            const float mu12 = mu1 * mu2;
            const float s1  = acc[o][2] - mu1s;
            const float s2  = acc[o][3] - mu2s;
            const float s12 = acc[o][4] - mu12;
            const float v1 = 2.f * s12 + C2;
            const float v2 = s1 + s2 + C2;
            cs_acc   += v1 / v2;
            ssim_acc += ((2.f * mu12 + C1) * v1) / ((mu1s + mu2s + C1) * v2);
        }
    }

    // ---- 5. block reduction
    #pragma unroll
    for (int off = 32; off > 0; off >>= 1) {
        ssim_acc += __shfl_down(ssim_acc, off);
        cs_acc   += __shfl_down(cs_acc, off);
    }
    const int wave = tid >> 6;
    if ((tid & 63) == 0) { wred[wave][0] = ssim_acc; wred[wave][1] = cs_acc; }
    __syncthreads();
    if (tid == 0) {
        const float s = wred[0][0] + wred[1][0] + wred[2][0] + wred[3][0];
        const float c = wred[0][1] + wred[1][1] + wred[2][1] + wred[3][1];
        atomicAdd(&sums[level],     (double)s);
        atomicAdd(&sums[5 + level], (double)c);
    }
}

// -------------------- final combine --------------------
__global__ void msssim_final_kernel(const double* __restrict__ sums,
                                    float* __restrict__ out)
{
    if (threadIdx.x == 0 && blockIdx.x == 0) {
        const double W[5] = {0.0448, 0.2856, 0.3001, 0.2363, 0.1333};
        const int Houts[5] = {502, 246, 118, 54, 22};
        double mssim[5], mcs[5];
        for (int l = 0; l < 5; ++l) {
            const double cnt = 48.0 * (double)Houts[l] * (double)Houts[l];
            mssim[l] = (sums[l]     / cnt + 1.0) * 0.5;
            mcs[l]   = (sums[5 + l] / cnt + 1.0) * 0.5;
        }
        const double p2 = pow(mssim[4], W[4]);
        double prod = 1.0;
        for (int l = 0; l < 4; ++l) prod *= pow(mcs[l], W[l]) * p2;
        out[0] = (float)(1.0 - prod);
    }
}

// -------------------- launch --------------------
extern "C" void kernel_launch(void* const* d_in, const int* in_sizes, int n_in,
                              void* d_out, int out_size, void* d_ws, size_t ws_size,
                              hipStream_t stream)
{
    const float* img1 = (const float*)d_in[0];
    const float* img2 = (const float*)d_in[1];
    float* out = (float*)d_out;
    (void)in_sizes; (void)n_in; (void)out_size; (void)ws_size;

    char* ws = (char*)d_ws;
    double* sums = (double*)ws;                      // 10 doubles
    float* X1 = (float*)(ws + 256);                  // 3,145,728 floats
    float* X2 = X1 + 3145728;
    float* Y1 = X2 + 3145728;                        // 786,432 floats
    float* Y2 = Y1 + 786432;

    hipMemsetAsync(sums, 0, 10 * sizeof(double), stream);

    auto launch_level = [&](const float* a, const float* b, int H, int level,
                            float* pa, float* pb) {
        const int Hout = H - HALO;
        const int t = (Hout + TILE - 1) / TILE;
        dim3 grid(t, t, 48);
        hipLaunchKernelGGL(msssim_level_kernel, grid, dim3(256), 0, stream,
                           a, b, H, level, sums, pa, pb);
    };

    launch_level(img1, img2, 512, 0, X1, X2);      // level 0, pool -> X (256)
    launch_level(X1, X2, 256, 1, Y1, Y2);          // level 1, pool -> Y (128)
    launch_level(Y1, Y2, 128, 2, X1, X2);          // level 2, pool -> X (64)
    launch_level(X1, X2, 64, 3, Y1, Y2);           // level 3, pool -> Y (32)
    launch_level(Y1, Y2, 32, 4, nullptr, nullptr); // level 4

    hipLaunchKernelGGL(msssim_final_kernel, dim3(1), dim3(64), 0, stream, sums, out);
}

// Round 5
// 444.978 us; speedup vs baseline: 3.3621x; 1.0224x over previous
//
#include <hip/hip_runtime.h>
#include <math.h>

#define TILE 32              // output tile (both dims)
#define IN_DIM 42            // staged rows (TILE + 10)
#define SCP 21               // staging col-pairs (42 cols)
#define HALO 10
#define S12 170              // per-colpair stride (words) of (h1,h2)/(h11,h22) arrays
#define S5 85                // per-colpair stride (words) of h12 array
#define ARR34_BASE 2720      // 16 * S12
#define ARR5_BASE 5440       // 2 * 2720
#define SMEM_WORDS 6800      // 5440 + 16*85 ; staging (3528) aliases the front

__device__ __forceinline__ float2 f2fma(float s, float2 v, float2 acc) {
    return make_float2(fmaf(s, v.x, acc.x), fmaf(s, v.y, acc.y));
}

// -------------------- fused SSIM-level (+pool) kernel --------------------
// Block: 32x32 output tile of one (b,c) plane, 256 threads.
// Phases: stage interleaved (A0,A1,B0,B1) -> sync -> pool + h-pass->regs ->
// sync -> h-write (channel-paired, conflict-free strides) -> sync -> v-pass
// (float2 packed accums) -> SSIM (fast rcp) -> reduce -> f64 atomics.
__global__ __launch_bounds__(256)
void msssim_level_kernel(const float* __restrict__ img1,
                         const float* __restrict__ img2,
                         int H, int level, double* __restrict__ sums,
                         float* __restrict__ pool1, float* __restrict__ pool2)
{
    __shared__ __align__(16) float smem[SMEM_WORDS];
    __shared__ float wred[4][2];

    const float g[11] = {0.00102838f, 0.00759875f, 0.03600077f, 0.10936070f,
                         0.21300554f, 0.26601173f, 0.21300554f, 0.10936070f,
                         0.03600077f, 0.00759875f, 0.00102838f};

    const int tid = threadIdx.x;
    const int Hout = H - HALO;
    const int oy0 = blockIdx.y * TILE;
    const int ox0 = blockIdx.x * TILE;
    const long long base = (long long)blockIdx.z * H * H;

    // ---- 1. stage 42 rows x 21 col-pairs, interleaved (A0,A1,B0,B1)
    for (int w = tid; w < IN_DIM * SCP; w += 256) {
        const int r = w / SCP, cp = w - r * SCP;
        const int y = oy0 + r, x = ox0 + 2 * cp;
        float2 a = make_float2(0.f, 0.f), b = make_float2(0.f, 0.f);
        if (y < H && x < H) {   // H,x even -> x+1 < H too
            const long long idx = base + (long long)y * H + x;
            a = *(const float2*)(img1 + idx);
            b = *(const float2*)(img2 + idx);
        }
        *(float4*)&smem[w * 4] = make_float4(a.x, a.y, b.x, b.y);
    }
    __syncthreads();

    // ---- 2. fused 2x2 avg pool (owned 32x32 input region -> 16x16)
    if (pool1 != nullptr) {
        const int pr = tid >> 4, pc = tid & 15;
        const int Hp = H >> 1;
        const int py = (oy0 >> 1) + pr, px = (ox0 >> 1) + pc;
        if (py < Hp && px < Hp) {
            const float4 v0 = *(const float4*)&smem[(2 * pr * SCP + pc) * 4];
            const float4 v1 = *(const float4*)&smem[((2 * pr + 1) * SCP + pc) * 4];
            const long long ob = (long long)blockIdx.z * Hp * Hp + (long long)py * Hp + px;
            pool1[ob] = 0.25f * (v0.x + v0.y + v1.x + v1.y);
            pool2[ob] = 0.25f * (v0.z + v0.w + v1.z + v1.w);
        }
    }

    // ---- 3. h-pass: 672 (row, colpair) positions, results to registers
    float hreg[3][10];
    #pragma unroll
    for (int t = 0; t < 3; ++t) {
        const int p = tid + 256 * t;
        if (p < IN_DIM * 16) {
            const int r = p >> 4, m = p & 15;
            float h1a = 0.f, h2a = 0.f, h11a = 0.f, h22a = 0.f, h12a = 0.f;
            float h1b = 0.f, h2b = 0.f, h11b = 0.f, h22b = 0.f, h12b = 0.f;
            #pragma unroll
            for (int tt = 0; tt < 6; ++tt) {
                const float4 v = *(const float4*)&smem[(r * SCP + m + tt) * 4];
                // packed q products (natural float2 pairs)
                const float q11x = v.x * v.x, q11y = v.y * v.y;
                const float q22x = v.z * v.z, q22y = v.w * v.w;
                const float q12x = v.x * v.z, q12y = v.y * v.w;
                // value j = 2*tt : col0 weight g[2tt]; col1 weight g[2tt-1]
                {
                    const float w0 = g[2 * tt];
                    h1a = fmaf(w0, v.x, h1a);   h2a = fmaf(w0, v.z, h2a);
                    h11a = fmaf(w0, q11x, h11a); h22a = fmaf(w0, q22x, h22a);
                    h12a = fmaf(w0, q12x, h12a);
                    if (tt >= 1) {
                        const float w1 = g[2 * tt - 1];
                        h1b = fmaf(w1, v.x, h1b);   h2b = fmaf(w1, v.z, h2b);
                        h11b = fmaf(w1, q11x, h11b); h22b = fmaf(w1, q22x, h22b);
                        h12b = fmaf(w1, q12x, h12b);
                    }
                }
                // value j = 2*tt+1 : col0 weight g[2tt+1] (tt<=4); col1 weight g[2tt]
                {
                    if (tt <= 4) {
                        const float w0 = g[2 * tt + 1];
                        h1a = fmaf(w0, v.y, h1a);   h2a = fmaf(w0, v.w, h2a);
                        h11a = fmaf(w0, q11y, h11a); h22a = fmaf(w0, q22y, h22a);
                        h12a = fmaf(w0, q12y, h12a);
                    }
                    const float w1 = g[2 * tt];
                    h1b = fmaf(w1, v.y, h1b);   h2b = fmaf(w1, v.w, h2b);
                    h11b = fmaf(w1, q11y, h11b); h22b = fmaf(w1, q22y, h22b);
                    h12b = fmaf(w1, q12y, h12b);
                }
            }
            hreg[t][0] = h1a;  hreg[t][1] = h2a;
            hreg[t][2] = h11a; hreg[t][3] = h22a; hreg[t][4] = h12a;
            hreg[t][5] = h1b;  hreg[t][6] = h2b;
            hreg[t][7] = h11b; hreg[t][8] = h22b; hreg[t][9] = h12b;
        }
    }
    __syncthreads();   // all staging reads done; safe to overwrite

    // ---- 4. h-write: channel-paired, conflict-free strides
    #pragma unroll
    for (int t = 0; t < 3; ++t) {
        const int p = tid + 256 * t;
        if (p < IN_DIM * 16) {
            const int r = p >> 4, m = p & 15;
            const int b12 = m * S12 + r * 4;
            *(float2*)&smem[b12]                  = make_float2(hreg[t][0], hreg[t][1]);
            *(float2*)&smem[b12 + 2]              = make_float2(hreg[t][5], hreg[t][6]);
            *(float2*)&smem[ARR34_BASE + b12]     = make_float2(hreg[t][2], hreg[t][3]);
            *(float2*)&smem[ARR34_BASE + b12 + 2] = make_float2(hreg[t][7], hreg[t][8]);
            const int b5 = ARR5_BASE + m * S5 + r * 2;
            smem[b5]     = hreg[t][4];
            smem[b5 + 1] = hreg[t][9];
        }
    }
    __syncthreads();

    // ---- 5. v-pass: thread = (col tx, rows r0..r0+3), packed accumulators
    const int tx = tid & 31, rg = tid >> 5;
    const int r0 = rg * 4;
    const int m = tx >> 1, par = tx & 1;
    const int b12 = m * S12 + par * 2;
    const int b34 = ARR34_BASE + b12;
    const int b5  = ARR5_BASE + m * S5 + par;

    float2 accA[4], accB[4];
    float accC[4];
    #pragma unroll
    for (int o = 0; o < 4; ++o) {
        accA[o] = make_float2(0.f, 0.f);
        accB[o] = make_float2(0.f, 0.f);
        accC[o] = 0.f;
    }

    #pragma unroll
    for (int i = 0; i < 14; ++i) {
        const float2 p12 = *(const float2*)&smem[b12 + (r0 + i) * 4];
        const float2 p34 = *(const float2*)&smem[b34 + (r0 + i) * 4];
        const float  p5  = smem[b5 + (r0 + i) * 2];
        #pragma unroll
        for (int o = 0; o < 4; ++o) {
            const int k = i - o;
            if (k >= 0 && k <= 10) {   // compile-time resolved
                const float w = g[k];
                accA[o] = f2fma(w, p12, accA[o]);
                accB[o] = f2fma(w, p34, accB[o]);
                accC[o] = fmaf(w, p5, accC[o]);
            }
        }
    }

    // ---- 6. SSIM pointwise (fast rcp) + accumulate
    const float C1 = 4.0e-4f;   // (0.01*2)^2
    const float C2 = 3.6e-3f;   // (0.03*2)^2
    float ssim_acc = 0.f, cs_acc = 0.f;
    const int ox = ox0 + tx;
    #pragma unroll
    for (int o = 0; o < 4; ++o) {
        const int oy = oy0 + r0 + o;
        if (oy < Hout && ox < Hout) {
            const float mu1 = accA[o].x, mu2 = accA[o].y;
            const float mu1s = mu1 * mu1;
            const float mu2s = mu2 * mu2;
            const float mu12 = mu1 * mu2;
            const float v1 = 2.f * (accC[o] - mu12) + C2;
            const float v2 = (accB[o].x - mu1s) + (accB[o].y - mu2s) + C2;
            cs_acc += v1 * __builtin_amdgcn_rcpf(v2);
            const float den = (mu1s + mu2s + C1) * v2;
            ssim_acc += (2.f * mu12 + C1) * v1 * __builtin_amdgcn_rcpf(den);
        }
    }

    // ---- 7. block reduction
    #pragma unroll
    for (int off = 32; off > 0; off >>= 1) {
        ssim_acc += __shfl_down(ssim_acc, off);
        cs_acc   += __shfl_down(cs_acc, off);
    }
    const int wave = tid >> 6;
    if ((tid & 63) == 0) { wred[wave][0] = ssim_acc; wred[wave][1] = cs_acc; }
    __syncthreads();
    if (tid == 0) {
        const float s = wred[0][0] + wred[1][0] + wred[2][0] + wred[3][0];
        const float c = wred[0][1] + wred[1][1] + wred[2][1] + wred[3][1];
        atomicAdd(&sums[level],     (double)s);
        atomicAdd(&sums[5 + level], (double)c);
    }
}

// -------------------- final combine --------------------
__global__ void msssim_final_kernel(const double* __restrict__ sums,
                                    float* __restrict__ out)
{
    if (threadIdx.x == 0 && blockIdx.x == 0) {
        const double W[5] = {0.0448, 0.2856, 0.3001, 0.2363, 0.1333};
        const int Houts[5] = {502, 246, 118, 54, 22};
        double mssim[5], mcs[5];
        for (int l = 0; l < 5; ++l) {
            const double cnt = 48.0 * (double)Houts[l] * (double)Houts[l];
            mssim[l] = (sums[l]     / cnt + 1.0) * 0.5;
            mcs[l]   = (sums[5 + l] / cnt + 1.0) * 0.5;
        }
        const double p2 = pow(mssim[4], W[4]);
        double prod = 1.0;
        for (int l = 0; l < 4; ++l) prod *= pow(mcs[l], W[l]) * p2;
        out[0] = (float)(1.0 - prod);
    }
}

// -------------------- launch --------------------
extern "C" void kernel_launch(void* const* d_in, const int* in_sizes, int n_in,
                              void* d_out, int out_size, void* d_ws, size_t ws_size,
                              hipStream_t stream)
{
    const float* img1 = (const float*)d_in[0];
    const float* img2 = (const float*)d_in[1];
    float* out = (float*)d_out;
    (void)in_sizes; (void)n_in; (void)out_size; (void)ws_size;

    char* ws = (char*)d_ws;
    double* sums = (double*)ws;                      // 10 doubles
    float* X1 = (float*)(ws + 256);                  // 3,145,728 floats
    float* X2 = X1 + 3145728;
    float* Y1 = X2 + 3145728;                        // 786,432 floats
    float* Y2 = Y1 + 786432;

    hipMemsetAsync(sums, 0, 10 * sizeof(double), stream);

    auto launch_level = [&](const float* a, const float* b, int H, int level,
                            float* pa, float* pb) {
        const int Hout = H - HALO;
        const int t = (Hout + TILE - 1) / TILE;
        dim3 grid(t, t, 48);
        hipLaunchKernelGGL(msssim_level_kernel, grid, dim3(256), 0, stream,
                           a, b, H, level, sums, pa, pb);
    };

    launch_level(img1, img2, 512, 0, X1, X2);      // level 0, pool -> X (256)
    launch_level(X1, X2, 256, 1, Y1, Y2);          // level 1, pool -> Y (128)
    launch_level(Y1, Y2, 128, 2, X1, X2);          // level 2, pool -> X (64)
    launch_level(X1, X2, 64, 3, Y1, Y2);           // level 3, pool -> Y (32)
    launch_level(Y1, Y2, 32, 4, nullptr, nullptr); // level 4

    hipLaunchKernelGGL(msssim_final_kernel, dim3(1), dim3(64), 0, stream, sums, out);
}

// Round 6
// 186.120 us; speedup vs baseline: 8.0381x; 2.3908x over previous
//
#include <hip/hip_runtime.h>
#include <math.h>

#define TILE 32              // output tile (both dims)
#define IN_DIM 42            // staged rows per tile (TILE + 10)
#define SCP 21               // staging col-pairs (42 cols)
#define HALO 10
#define STAGE_WORDS (IN_DIM * SCP * 4)        // 3528: staging region
#define S12 170              // per-colpair stride (words) of (h1,h2)/(h11,h22)
#define S5  85               // per-colpair stride (words) of h12
#define H12_BASE STAGE_WORDS                  // 3528
#define H34_BASE (H12_BASE + 16 * S12)        // 6248
#define H5_BASE  (H34_BASE + 16 * S12)        // 8968
#define SMEM_WORDS (H5_BASE + 16 * S5)        // 10328 words = 41312 B -> 3 blocks/CU

__device__ __forceinline__ float2 f2fma(float s, float2 v, float2 acc) {
    return make_float2(fmaf(s, v.x, acc.x), fmaf(s, v.y, acc.y));
}

// -------------------- persistent fused SSIM-level (+pool) kernel --------------------
// Block = one 32-col output strip of one (b,c) plane; loops over all row-tiles.
// Per tile iteration (2 barriers):
//   A: prefetch next tile (global->regs) | pool from staging | h-pass staging->regs
//   B: h-write regs->h-LDS | staging-write prefetched regs->staging-LDS
//   C: v-pass h-LDS->SSIM, accumulate in registers
// Block-level reduce + 2 double atomics once at the end.
__global__ __launch_bounds__(256)
void msssim_level_kernel(const float* __restrict__ img1,
                         const float* __restrict__ img2,
                         int H, int level, double* __restrict__ sums,
                         float* __restrict__ pool1, float* __restrict__ pool2)
{
    __shared__ __align__(16) float smem[SMEM_WORDS];
    __shared__ float wred[4][2];

    const float g[11] = {0.00102838f, 0.00759875f, 0.03600077f, 0.10936070f,
                         0.21300554f, 0.26601173f, 0.21300554f, 0.10936070f,
                         0.03600077f, 0.00759875f, 0.00102838f};

    const int tid = threadIdx.x;
    const int Hout = H - HALO;
    const int ntiles = (Hout + TILE - 1) / TILE;
    const int ox0 = blockIdx.x * TILE;
    const int Hp = H >> 1;
    const long long base = (long long)blockIdx.y * H * H;

    // ---- per-thread staging slots (fixed across tiles): slot s = tid + 256*t
    int rHS[4];   // r * H  (row-within-tile premultiplied)
    int rS[4];    // r (or -1 if slot unused)
    int xS[4];    // absolute x of first col (or guard via x<H)
    #pragma unroll
    for (int t4 = 0; t4 < 4; ++t4) {
        const int s = tid + 256 * t4;
        if (s < IN_DIM * SCP) {
            const int r = s / SCP, cp = s - r * SCP;
            rS[t4] = r; rHS[t4] = r * H; xS[t4] = ox0 + 2 * cp;
        } else {
            rS[t4] = -1; rHS[t4] = 0; xS[t4] = 0;
        }
    }

    float4 pref[4];
    // ---- prologue: load + stage tile 0
    {
        #pragma unroll
        for (int t4 = 0; t4 < 4; ++t4) {
            float2 a = make_float2(0.f, 0.f), b = make_float2(0.f, 0.f);
            if (rS[t4] >= 0) {
                const int y = rS[t4], x = xS[t4];
                if (y < H && x < H) {
                    const long long idx = base + rHS[t4] + x;
                    a = *(const float2*)(img1 + idx);
                    b = *(const float2*)(img2 + idx);
                }
            }
            pref[t4] = make_float4(a.x, a.y, b.x, b.y);
        }
        #pragma unroll
        for (int t4 = 0; t4 < 4; ++t4)
            if (rS[t4] >= 0) *(float4*)&smem[(tid + 256 * t4) * 4] = pref[t4];
    }
    __syncthreads();

    float ssim_acc = 0.f, cs_acc = 0.f;

    for (int tt = 0; tt < ntiles; ++tt) {
        const int ty0 = tt * TILE;
        const bool more = (tt + 1 < ntiles);

        // ---- phase A: prefetch next tile into regs (latency hides under h-pass)
        if (more) {
            const long long rowbase = base + (long long)(ty0 + TILE) * H;
            #pragma unroll
            for (int t4 = 0; t4 < 4; ++t4) {
                float2 a = make_float2(0.f, 0.f), b = make_float2(0.f, 0.f);
                if (rS[t4] >= 0) {
                    const int y = ty0 + TILE + rS[t4], x = xS[t4];
                    if (y < H && x < H) {
                        const long long idx = rowbase + rHS[t4] + x;
                        a = *(const float2*)(img1 + idx);
                        b = *(const float2*)(img2 + idx);
                    }
                }
                pref[t4] = make_float4(a.x, a.y, b.x, b.y);
            }
        }

        // ---- phase A: fused 2x2 avg pool (owned 32x32 input region -> 16x16)
        if (pool1 != nullptr) {
            const int pr = tid >> 4, pc = tid & 15;
            const int py = (ty0 >> 1) + pr, px = (ox0 >> 1) + pc;
            if (py < Hp && px < Hp) {
                const float4 v0 = *(const float4*)&smem[(2 * pr * SCP + pc) * 4];
                const float4 v1 = *(const float4*)&smem[((2 * pr + 1) * SCP + pc) * 4];
                const long long ob = (long long)blockIdx.y * Hp * Hp + (long long)py * Hp + px;
                pool1[ob] = 0.25f * (v0.x + v0.y + v1.x + v1.y);
                pool2[ob] = 0.25f * (v0.z + v0.w + v1.z + v1.w);
            }
        }

        // ---- phase A: h-pass, 672 (row, colpair) positions -> registers
        float hreg[3][10];
        #pragma unroll
        for (int t = 0; t < 3; ++t) {
            const int p = tid + 256 * t;
            if (p < IN_DIM * 16) {
                const int r = p >> 4, m = p & 15;
                float h1a = 0.f, h2a = 0.f, h11a = 0.f, h22a = 0.f, h12a = 0.f;
                float h1b = 0.f, h2b = 0.f, h11b = 0.f, h22b = 0.f, h12b = 0.f;
                #pragma unroll
                for (int jj = 0; jj < 6; ++jj) {
                    const float4 v = *(const float4*)&smem[(r * SCP + m + jj) * 4];
                    const float q11x = v.x * v.x, q11y = v.y * v.y;
                    const float q22x = v.z * v.z, q22y = v.w * v.w;
                    const float q12x = v.x * v.z, q12y = v.y * v.w;
                    {
                        const float w0 = g[2 * jj];
                        h1a = fmaf(w0, v.x, h1a);   h2a = fmaf(w0, v.z, h2a);
                        h11a = fmaf(w0, q11x, h11a); h22a = fmaf(w0, q22x, h22a);
                        h12a = fmaf(w0, q12x, h12a);
                        if (jj >= 1) {
                            const float w1 = g[2 * jj - 1];
                            h1b = fmaf(w1, v.x, h1b);   h2b = fmaf(w1, v.z, h2b);
                            h11b = fmaf(w1, q11x, h11b); h22b = fmaf(w1, q22x, h22b);
                            h12b = fmaf(w1, q12x, h12b);
                        }
                    }
                    {
                        if (jj <= 4) {
                            const float w0 = g[2 * jj + 1];
                            h1a = fmaf(w0, v.y, h1a);   h2a = fmaf(w0, v.w, h2a);
                            h11a = fmaf(w0, q11y, h11a); h22a = fmaf(w0, q22y, h22a);
                            h12a = fmaf(w0, q12y, h12a);
                        }
                        const float w1 = g[2 * jj];
                        h1b = fmaf(w1, v.y, h1b);   h2b = fmaf(w1, v.w, h2b);
                        h11b = fmaf(w1, q11y, h11b); h22b = fmaf(w1, q22y, h22b);
                        h12b = fmaf(w1, q12y, h12b);
                    }
                }
                hreg[t][0] = h1a;  hreg[t][1] = h2a;
                hreg[t][2] = h11a; hreg[t][3] = h22a; hreg[t][4] = h12a;
                hreg[t][5] = h1b;  hreg[t][6] = h2b;
                hreg[t][7] = h11b; hreg[t][8] = h22b; hreg[t][9] = h12b;
            }
        }
        __syncthreads();   // staging reads done; h-LDS reads (prev C) done

        // ---- phase B: h-write (conflict-free strides) + stage next tile
        #pragma unroll
        for (int t = 0; t < 3; ++t) {
            const int p = tid + 256 * t;
            if (p < IN_DIM * 16) {
                const int r = p >> 4, m = p & 15;
                const int b12 = H12_BASE + m * S12 + r * 4;
                *(float2*)&smem[b12]     = make_float2(hreg[t][0], hreg[t][1]);
                *(float2*)&smem[b12 + 2] = make_float2(hreg[t][5], hreg[t][6]);
                const int b34 = H34_BASE + m * S12 + r * 4;
                *(float2*)&smem[b34]     = make_float2(hreg[t][2], hreg[t][3]);
                *(float2*)&smem[b34 + 2] = make_float2(hreg[t][7], hreg[t][8]);
                const int b5 = H5_BASE + m * S5 + r * 2;
                smem[b5]     = hreg[t][4];
                smem[b5 + 1] = hreg[t][9];
            }
        }
        if (more) {
            #pragma unroll
            for (int t4 = 0; t4 < 4; ++t4)
                if (rS[t4] >= 0) *(float4*)&smem[(tid + 256 * t4) * 4] = pref[t4];
        }
        __syncthreads();

        // ---- phase C: v-pass + SSIM accumulate
        const int tx = tid & 31, rg = tid >> 5;
        const int r0 = rg * 4;
        const int m = tx >> 1, par = tx & 1;
        const int b12 = H12_BASE + m * S12 + par * 2;
        const int b34 = H34_BASE + m * S12 + par * 2;
        const int b5  = H5_BASE + m * S5 + par;

        float2 accA[4], accB[4];
        float accC[4];
        #pragma unroll
        for (int o = 0; o < 4; ++o) {
            accA[o] = make_float2(0.f, 0.f);
            accB[o] = make_float2(0.f, 0.f);
            accC[o] = 0.f;
        }
        #pragma unroll
        for (int i = 0; i < 14; ++i) {
            const float2 p12 = *(const float2*)&smem[b12 + (r0 + i) * 4];
            const float2 p34 = *(const float2*)&smem[b34 + (r0 + i) * 4];
            const float  p5  = smem[b5 + (r0 + i) * 2];
            #pragma unroll
            for (int o = 0; o < 4; ++o) {
                const int k = i - o;
                if (k >= 0 && k <= 10) {
                    const float w = g[k];
                    accA[o] = f2fma(w, p12, accA[o]);
                    accB[o] = f2fma(w, p34, accB[o]);
                    accC[o] = fmaf(w, p5, accC[o]);
                }
            }
        }

        const float C1 = 4.0e-4f;   // (0.01*2)^2
        const float C2 = 3.6e-3f;   // (0.03*2)^2
        const int ox = ox0 + tx;
        #pragma unroll
        for (int o = 0; o < 4; ++o) {
            const int oy = ty0 + r0 + o;
            if (oy < Hout && ox < Hout) {
                const float mu1 = accA[o].x, mu2 = accA[o].y;
                const float mu1s = mu1 * mu1;
                const float mu2s = mu2 * mu2;
                const float mu12 = mu1 * mu2;
                const float v1 = 2.f * (accC[o] - mu12) + C2;
                const float v2 = (accB[o].x - mu1s) + (accB[o].y - mu2s) + C2;
                cs_acc += v1 * __builtin_amdgcn_rcpf(v2);
                const float den = (mu1s + mu2s + C1) * v2;
                ssim_acc += (2.f * mu12 + C1) * v1 * __builtin_amdgcn_rcpf(den);
            }
        }
        // no barrier here: next phase A doesn't touch h-LDS; staging already
        // holds tile tt+1 (written in phase B); h-LDS rewritten only after
        // next iteration's barrier.
    }

    // ---- block reduction + single pair of f64 atomics
    #pragma unroll
    for (int off = 32; off > 0; off >>= 1) {
        ssim_acc += __shfl_down(ssim_acc, off);
        cs_acc   += __shfl_down(cs_acc, off);
    }
    const int wave = tid >> 6;
    if ((tid & 63) == 0) { wred[wave][0] = ssim_acc; wred[wave][1] = cs_acc; }
    __syncthreads();
    if (tid == 0) {
        const float s = wred[0][0] + wred[1][0] + wred[2][0] + wred[3][0];
        const float c = wred[0][1] + wred[1][1] + wred[2][1] + wred[3][1];
        atomicAdd(&sums[level],     (double)s);
        atomicAdd(&sums[5 + level], (double)c);
    }
}

// -------------------- final combine --------------------
__global__ void msssim_final_kernel(const double* __restrict__ sums,
                                    float* __restrict__ out)
{
    if (threadIdx.x == 0 && blockIdx.x == 0) {
        const double W[5] = {0.0448, 0.2856, 0.3001, 0.2363, 0.1333};
        const int Houts[5] = {502, 246, 118, 54, 22};
        double mssim[5], mcs[5];
        for (int l = 0; l < 5; ++l) {
            const double cnt = 48.0 * (double)Houts[l] * (double)Houts[l];
            mssim[l] = (sums[l]     / cnt + 1.0) * 0.5;
            mcs[l]   = (sums[5 + l] / cnt + 1.0) * 0.5;
        }
        const double p2 = pow(mssim[4], W[4]);
        double prod = 1.0;
        for (int l = 0; l < 4; ++l) prod *= pow(mcs[l], W[l]) * p2;
        out[0] = (float)(1.0 - prod);
    }
}

// -------------------- launch --------------------
extern "C" void kernel_launch(void* const* d_in, const int* in_sizes, int n_in,
                              void* d_out, int out_size, void* d_ws, size_t ws_size,
                              hipStream_t stream)
{
    const float* img1 = (const float*)d_in[0];
    const float* img2 = (const float*)d_in[1];
    float* out = (float*)d_out;
    (void)in_sizes; (void)n_in; (void)out_size; (void)ws_size;

    char* ws = (char*)d_ws;
    double* sums = (double*)ws;                      // 10 doubles
    float* X1 = (float*)(ws + 256);                  // 3,145,728 floats
    float* X2 = X1 + 3145728;
    float* Y1 = X2 + 3145728;                        // 786,432 floats
    float* Y2 = Y1 + 786432;

    hipMemsetAsync(sums, 0, 10 * sizeof(double), stream);

    auto launch_level = [&](const float* a, const float* b, int H, int level,
                            float* pa, float* pb) {
        const int Hout = H - HALO;
        const int strips = (Hout + TILE - 1) / TILE;
        dim3 grid(strips, 48);                       // persistent column strips
        hipLaunchKernelGGL(msssim_level_kernel, grid, dim3(256), 0, stream,
                           a, b, H, level, sums, pa, pb);
    };

    launch_level(img1, img2, 512, 0, X1, X2);      // level 0, pool -> X (256)
    launch_level(X1, X2, 256, 1, Y1, Y2);          // level 1, pool -> Y (128)
    launch_level(Y1, Y2, 128, 2, X1, X2);          // level 2, pool -> X (64)
    launch_level(X1, X2, 64, 3, Y1, Y2);           // level 3, pool -> Y (32)
    launch_level(Y1, Y2, 32, 4, nullptr, nullptr); // level 4

    hipLaunchKernelGGL(msssim_final_kernel, dim3(1), dim3(64), 0, stream, sums, out);
}

// Round 7
// 178.692 us; speedup vs baseline: 8.3723x; 1.0416x over previous
//
#include <hip/hip_runtime.h>
#include <math.h>

#define TILE 32              // output tile (both dims)
#define IN_DIM 42            // staged rows per tile (TILE + 10)
#define SCP 21               // staging col-pairs (42 cols)
#define HALO 10
#define STAGE_WORDS (IN_DIM * SCP * 4)        // 3528: staging region
#define S12 170              // per-colpair stride (words) of (h1,h2)/(h11,h22)
#define S5  85               // per-colpair stride (words) of h12
#define H12_BASE STAGE_WORDS                  // 3528
#define H34_BASE (H12_BASE + 16 * S12)        // 6248
#define H5_BASE  (H34_BASE + 16 * S12)        // 8968
#define SMEM_WORDS (H5_BASE + 16 * S5)        // 10328 words = 41312 B -> 3 blocks/CU

typedef float vf2 __attribute__((ext_vector_type(2)));

// CDNA packed dual-fp32 ops (VOP3P; hipcc never auto-emits these)
__device__ __forceinline__ vf2 pk_fma(vf2 a, vf2 b, vf2 c) {
    vf2 d;
    asm("v_pk_fma_f32 %0, %1, %2, %3" : "=v"(d) : "v"(a), "v"(b), "v"(c));
    return d;
}
__device__ __forceinline__ vf2 pk_mul(vf2 a, vf2 b) {
    vf2 d;
    asm("v_pk_mul_f32 %0, %1, %2" : "=v"(d) : "v"(a), "v"(b));
    return d;
}

// -------------------- persistent fused SSIM-level (+pool) kernel --------------------
// Block = 32-col strip x row-segment of one (b,c) plane; loops over its tiles.
// Per tile iteration (2 barriers):
//   A: prefetch next tile (global->regs) | pool from staging | h-pass staging->regs
//   B: h-write regs->h-LDS | staging-write prefetched regs->staging-LDS
//   C: v-pass h-LDS->SSIM, accumulate in registers
// Staging layout per (row, colpair): (A0, B0, A1, B1) so (A,B) pairs are
// adjacent VGPRs for v_pk ops. h layout: (h1,h2) pairs stride S12, (h11,h22)
// pairs stride S12, h12 scalars stride S5 (minimal bank aliasing).
__global__ __launch_bounds__(256)
void msssim_level_kernel(const float* __restrict__ img1,
                         const float* __restrict__ img2,
                         int H, int level, int tiles_per_seg,
                         double* __restrict__ sums,
                         float* __restrict__ pool1, float* __restrict__ pool2)
{
    __shared__ __align__(16) float smem[SMEM_WORDS];
    __shared__ float wred[4][2];

    const float g[11] = {0.00102838f, 0.00759875f, 0.03600077f, 0.10936070f,
                         0.21300554f, 0.26601173f, 0.21300554f, 0.10936070f,
                         0.03600077f, 0.00759875f, 0.00102838f};
    vf2 wg[11];
    #pragma unroll
    for (int k = 0; k < 11; ++k) { wg[k].x = g[k]; wg[k].y = g[k]; }

    const int tid = threadIdx.x;
    const int Hout = H - HALO;
    const int ntiles = (Hout + TILE - 1) / TILE;
    const int tstart = blockIdx.y * tiles_per_seg;
    const int tend = min(ntiles, tstart + tiles_per_seg);
    const int ox0 = blockIdx.x * TILE;
    const int Hp = H >> 1;
    const long long base = (long long)blockIdx.z * H * H;

    // ---- per-thread staging slots (fixed): slot s = tid + 256*t
    int rHS[4], rS[4], xS[4];
    #pragma unroll
    for (int t4 = 0; t4 < 4; ++t4) {
        const int s = tid + 256 * t4;
        if (s < IN_DIM * SCP) {
            const int r = s / SCP, cp = s - r * SCP;
            rS[t4] = r; rHS[t4] = r * H; xS[t4] = ox0 + 2 * cp;
        } else {
            rS[t4] = -1; rHS[t4] = 0; xS[t4] = 0;
        }
    }

    float4 pref[4];
    // ---- prologue: load + stage first tile (rows tstart*32 ..)
    {
        const long long rowbase = base + (long long)(tstart * TILE) * H;
        #pragma unroll
        for (int t4 = 0; t4 < 4; ++t4) {
            float2 a = make_float2(0.f, 0.f), b = make_float2(0.f, 0.f);
            if (rS[t4] >= 0) {
                const int y = tstart * TILE + rS[t4], x = xS[t4];
                if (y < H && x < H) {
                    const long long idx = rowbase + rHS[t4] + x;
                    a = *(const float2*)(img1 + idx);
                    b = *(const float2*)(img2 + idx);
                }
            }
            pref[t4] = make_float4(a.x, b.x, a.y, b.y);   // (A0,B0,A1,B1)
        }
        #pragma unroll
        for (int t4 = 0; t4 < 4; ++t4)
            if (rS[t4] >= 0) *(float4*)&smem[(tid + 256 * t4) * 4] = pref[t4];
    }
    __syncthreads();

    float ssim_acc = 0.f, cs_acc = 0.f;

    for (int tt = tstart; tt < tend; ++tt) {
        const int ty0 = tt * TILE;
        const bool more = (tt + 1 < tend);

        // ---- phase A: prefetch next tile into regs
        if (more) {
            const long long rowbase = base + (long long)(ty0 + TILE) * H;
            #pragma unroll
            for (int t4 = 0; t4 < 4; ++t4) {
                float2 a = make_float2(0.f, 0.f), b = make_float2(0.f, 0.f);
                if (rS[t4] >= 0) {
                    const int y = ty0 + TILE + rS[t4], x = xS[t4];
                    if (y < H && x < H) {
                        const long long idx = rowbase + rHS[t4] + x;
                        a = *(const float2*)(img1 + idx);
                        b = *(const float2*)(img2 + idx);
                    }
                }
                pref[t4] = make_float4(a.x, b.x, a.y, b.y);
            }
        }

        // ---- phase A: fused 2x2 avg pool (owned 32x32 input region -> 16x16)
        if (pool1 != nullptr) {
            const int pr = tid >> 4, pc = tid & 15;
            const int py = (ty0 >> 1) + pr, px = (ox0 >> 1) + pc;
            if (py < Hp && px < Hp) {
                const float4 v0 = *(const float4*)&smem[(2 * pr * SCP + pc) * 4];
                const float4 v1 = *(const float4*)&smem[((2 * pr + 1) * SCP + pc) * 4];
                const long long ob = (long long)blockIdx.z * Hp * Hp + (long long)py * Hp + px;
                pool1[ob] = 0.25f * (v0.x + v0.z + v1.x + v1.z);   // A0+A1
                pool2[ob] = 0.25f * (v0.y + v0.w + v1.y + v1.w);   // B0+B1
            }
        }

        // ---- phase A: h-pass, 672 (row, colpair) positions -> registers (pk math)
        vf2 h12a[3], h34a[3], h12b[3], h34b[3];
        float h5a[3], h5b[3];
        #pragma unroll
        for (int t = 0; t < 3; ++t) {
            const int p = tid + 256 * t;
            if (p < IN_DIM * 16) {
                const int r = p >> 4, m = p & 15;
                vf2 A12 = {0.f, 0.f}, A34 = {0.f, 0.f};
                vf2 B12 = {0.f, 0.f}, B34 = {0.f, 0.f};
                float A5 = 0.f, B5 = 0.f;
                #pragma unroll
                for (int jj = 0; jj < 6; ++jj) {
                    const float4 v = *(const float4*)&smem[(r * SCP + m + jj) * 4];
                    const vf2 lo = {v.x, v.y};          // (A_even, B_even)
                    const vf2 hi = {v.z, v.w};          // (A_odd,  B_odd)
                    const vf2 losq = pk_mul(lo, lo);    // (A^2, B^2)
                    const vf2 hisq = pk_mul(hi, hi);
                    const float loq12 = v.x * v.y;      // A*B
                    const float hiq12 = v.z * v.w;
                    // even value j = 2jj: col a weight g[j]; col b weight g[j-1]
                    {
                        A12 = pk_fma(wg[2 * jj], lo, A12);
                        A34 = pk_fma(wg[2 * jj], losq, A34);
                        A5 = fmaf(g[2 * jj], loq12, A5);
                        if (jj >= 1) {
                            B12 = pk_fma(wg[2 * jj - 1], lo, B12);
                            B34 = pk_fma(wg[2 * jj - 1], losq, B34);
                            B5 = fmaf(g[2 * jj - 1], loq12, B5);
                        }
                    }
                    // odd value j = 2jj+1: col a weight g[j] (jj<=4); col b weight g[j-1]
                    {
                        if (jj <= 4) {
                            A12 = pk_fma(wg[2 * jj + 1], hi, A12);
                            A34 = pk_fma(wg[2 * jj + 1], hisq, A34);
                            A5 = fmaf(g[2 * jj + 1], hiq12, A5);
                        }
                        B12 = pk_fma(wg[2 * jj], hi, B12);
                        B34 = pk_fma(wg[2 * jj], hisq, B34);
                        B5 = fmaf(g[2 * jj], hiq12, B5);
                    }
                }
                h12a[t] = A12; h34a[t] = A34; h5a[t] = A5;
                h12b[t] = B12; h34b[t] = B34; h5b[t] = B5;
            }
        }
        __syncthreads();   // staging reads done; h-LDS reads (prev C) done

        // ---- phase B: h-write + stage next tile
        #pragma unroll
        for (int t = 0; t < 3; ++t) {
            const int p = tid + 256 * t;
            if (p < IN_DIM * 16) {
                const int r = p >> 4, m = p & 15;
                const int b12 = H12_BASE + m * S12 + r * 4;
                *(vf2*)&smem[b12]     = h12a[t];
                *(vf2*)&smem[b12 + 2] = h12b[t];
                const int b34 = H34_BASE + m * S12 + r * 4;
                *(vf2*)&smem[b34]     = h34a[t];
                *(vf2*)&smem[b34 + 2] = h34b[t];
                const int b5 = H5_BASE + m * S5 + r * 2;
                smem[b5]     = h5a[t];
                smem[b5 + 1] = h5b[t];
            }
        }
        if (more) {
            #pragma unroll
            for (int t4 = 0; t4 < 4; ++t4)
                if (rS[t4] >= 0) *(float4*)&smem[(tid + 256 * t4) * 4] = pref[t4];
        }
        __syncthreads();

        // ---- phase C: v-pass (pk accumulators) + SSIM
        const int tx = tid & 31, rg = tid >> 5;
        const int r0 = rg * 4;
        const int m = tx >> 1, par = tx & 1;
        const int b12 = H12_BASE + m * S12 + par * 2;
        const int b34 = H34_BASE + m * S12 + par * 2;
        const int b5  = H5_BASE + m * S5 + par;

        vf2 accA[4], accB[4];
        float accC[4];
        #pragma unroll
        for (int o = 0; o < 4; ++o) {
            accA[o] = (vf2){0.f, 0.f};
            accB[o] = (vf2){0.f, 0.f};
            accC[o] = 0.f;
        }
        #pragma unroll
        for (int i = 0; i < 14; ++i) {
            const vf2 p12 = *(const vf2*)&smem[b12 + (r0 + i) * 4];
            const vf2 p34 = *(const vf2*)&smem[b34 + (r0 + i) * 4];
            const float p5 = smem[b5 + (r0 + i) * 2];
            #pragma unroll
            for (int o = 0; o < 4; ++o) {
                const int k = i - o;
                if (k >= 0 && k <= 10) {
                    accA[o] = pk_fma(wg[k], p12, accA[o]);
                    accB[o] = pk_fma(wg[k], p34, accB[o]);
                    accC[o] = fmaf(g[k], p5, accC[o]);
                }
            }
        }

        const float C1 = 4.0e-4f;   // (0.01*2)^2
        const float C2 = 3.6e-3f;   // (0.03*2)^2
        const int ox = ox0 + tx;
        #pragma unroll
        for (int o = 0; o < 4; ++o) {
            const int oy = ty0 + r0 + o;
            if (oy < Hout && ox < Hout) {
                const float mu1 = accA[o].x, mu2 = accA[o].y;
                const float mu1s = mu1 * mu1;
                const float mu2s = mu2 * mu2;
                const float mu12 = mu1 * mu2;
                const float v1 = 2.f * (accC[o] - mu12) + C2;
                const float v2 = (accB[o].x - mu1s) + (accB[o].y - mu2s) + C2;
                cs_acc += v1 * __builtin_amdgcn_rcpf(v2);
                const float den = (mu1s + mu2s + C1) * v2;
                ssim_acc += (2.f * mu12 + C1) * v1 * __builtin_amdgcn_rcpf(den);
            }
        }
        // no barrier: next phase A reads staging (already holds tile tt+1) and
        // h-LDS is only rewritten after the next iteration's first barrier.
    }

    // ---- block reduction + single pair of f64 atomics
    #pragma unroll
    for (int off = 32; off > 0; off >>= 1) {
        ssim_acc += __shfl_down(ssim_acc, off);
        cs_acc   += __shfl_down(cs_acc, off);
    }
    const int wave = tid >> 6;
    if ((tid & 63) == 0) { wred[wave][0] = ssim_acc; wred[wave][1] = cs_acc; }
    __syncthreads();
    if (tid == 0) {
        const float s = wred[0][0] + wred[1][0] + wred[2][0] + wred[3][0];
        const float c = wred[0][1] + wred[1][1] + wred[2][1] + wred[3][1];
        atomicAdd(&sums[level],     (double)s);
        atomicAdd(&sums[5 + level], (double)c);
    }
}

// -------------------- final combine --------------------
__global__ void msssim_final_kernel(const double* __restrict__ sums,
                                    float* __restrict__ out)
{
    if (threadIdx.x == 0 && blockIdx.x == 0) {
        const double W[5] = {0.0448, 0.2856, 0.3001, 0.2363, 0.1333};
        const int Houts[5] = {502, 246, 118, 54, 22};
        double mssim[5], mcs[5];
        for (int l = 0; l < 5; ++l) {
            const double cnt = 48.0 * (double)Houts[l] * (double)Houts[l];
            mssim[l] = (sums[l]     / cnt + 1.0) * 0.5;
            mcs[l]   = (sums[5 + l] / cnt + 1.0) * 0.5;
        }
        const double p2 = pow(mssim[4], W[4]);
        double prod = 1.0;
        for (int l = 0; l < 4; ++l) prod *= pow(mcs[l], W[l]) * p2;
        out[0] = (float)(1.0 - prod);
    }
}

// -------------------- launch --------------------
extern "C" void kernel_launch(void* const* d_in, const int* in_sizes, int n_in,
                              void* d_out, int out_size, void* d_ws, size_t ws_size,
                              hipStream_t stream)
{
    const float* img1 = (const float*)d_in[0];
    const float* img2 = (const float*)d_in[1];
    float* out = (float*)d_out;
    (void)in_sizes; (void)n_in; (void)out_size; (void)ws_size;

    char* ws = (char*)d_ws;
    double* sums = (double*)ws;                      // 10 doubles
    float* X1 = (float*)(ws + 256);                  // 3,145,728 floats
    float* X2 = X1 + 3145728;
    float* Y1 = X2 + 3145728;                        // 786,432 floats
    float* Y2 = Y1 + 786432;

    hipMemsetAsync(sums, 0, 10 * sizeof(double), stream);

    // segs chosen so blocks >= ~768 (3/CU) where the level has enough tiles:
    // L0: 16x1, L1: 8x2, L2: 4x4, L3: 2x2, L4: 1x1
    auto launch_level = [&](const float* a, const float* b, int H, int level,
                            int segs, float* pa, float* pb) {
        const int Hout = H - HALO;
        const int strips = (Hout + TILE - 1) / TILE;
        const int ntiles = (Hout + TILE - 1) / TILE;
        const int tps = (ntiles + segs - 1) / segs;
        dim3 grid(strips, segs, 48);
        hipLaunchKernelGGL(msssim_level_kernel, grid, dim3(256), 0, stream,
                           a, b, H, level, tps, sums, pa, pb);
    };

    launch_level(img1, img2, 512, 0, 1, X1, X2);      // level 0 -> X (256)
    launch_level(X1, X2, 256, 1, 2, Y1, Y2);          // level 1 -> Y (128)
    launch_level(Y1, Y2, 128, 2, 4, X1, X2);          // level 2 -> X (64)
    launch_level(X1, X2, 64, 3, 2, Y1, Y2);           // level 3 -> Y (32)
    launch_level(Y1, Y2, 32, 4, 1, nullptr, nullptr); // level 4

    hipLaunchKernelGGL(msssim_final_kernel, dim3(1), dim3(64), 0, stream, sums, out);
}

// Round 8
// 162.471 us; speedup vs baseline: 9.2082x; 1.0998x over previous
//
#include <hip/hip_runtime.h>
#include <math.h>

#define TILE 32              // output tile (both dims)
#define IN_DIM 42            // staged rows per tile (TILE + 10)
#define SCP 21               // staging col-pairs (42 cols)
#define HALO 10
#define STAGE_WORDS (IN_DIM * SCP * 4)        // 3528: staging region (P0,Q0,P1,Q1)
#define S12 170              // per-colpair stride (words) of h arrays
#define HPQ_BASE STAGE_WORDS                  // 3528: (hP,hQ) pairs
#define HSQ_BASE (HPQ_BASE + 16 * S12)        // 6248: (hP2,hQ2) pairs
#define SMEM_WORDS (HSQ_BASE + 16 * S12)      // 8968 words = 35872 B -> 4 blocks/CU

typedef float vf2 __attribute__((ext_vector_type(2)));

// CDNA packed dual-fp32 ops (VOP3P; hipcc never auto-emits these)
__device__ __forceinline__ vf2 pk_fma(vf2 a, vf2 b, vf2 c) {
    vf2 d;
    asm("v_pk_fma_f32 %0, %1, %2, %3" : "=v"(d) : "v"(a), "v"(b), "v"(c));
    return d;
}
__device__ __forceinline__ vf2 pk_mul(vf2 a, vf2 b) {
    vf2 d;
    asm("v_pk_mul_f32 %0, %1, %2" : "=v"(d) : "v"(a), "v"(b));
    return d;
}

// -------------------- persistent fused SSIM-level (+pool) kernel --------------------
// Polarization trick: P=A+B, Q=A-B. SSIM needs only conv(P),conv(Q),
// conv(P^2),conv(Q^2):
//   mu1*mu2        = (cP^2 - cQ^2)/4      mu1^2+mu2^2 = (cP^2 + cQ^2)/2
//   s1+s2          = (sP + sQ)/2          2*s12       = (sP - sQ)/2
// where sP = conv(P^2)-cP^2, sQ = conv(Q^2)-cQ^2.
// Pooling is linear, so levels >=1 consume pre-transformed (P,Q) planes.
// Block = 32-col strip x row-segment of one (b,c) plane; loops over tiles.
// Per tile (2 barriers): A: prefetch next tile->regs | pool | h-pass->regs;
// B: h-write + staging-write; C: v-pass + SSIM accumulate (registers).
__global__ __launch_bounds__(256)
void msssim_level_kernel(const float* __restrict__ src1,
                         const float* __restrict__ src2,
                         int H, int level, int tiles_per_seg, int pq_input,
                         double* __restrict__ sums,
                         float* __restrict__ pool1, float* __restrict__ pool2)
{
    __shared__ __align__(16) float smem[SMEM_WORDS];
    __shared__ float wred[4][2];

    const float g[11] = {0.00102838f, 0.00759875f, 0.03600077f, 0.10936070f,
                         0.21300554f, 0.26601173f, 0.21300554f, 0.10936070f,
                         0.03600077f, 0.00759875f, 0.00102838f};
    vf2 wg[11];
    #pragma unroll
    for (int k = 0; k < 11; ++k) { wg[k].x = g[k]; wg[k].y = g[k]; }

    const int tid = threadIdx.x;
    const int Hout = H - HALO;
    const int ntiles = (Hout + TILE - 1) / TILE;
    const int tstart = blockIdx.y * tiles_per_seg;
    const int tend = min(ntiles, tstart + tiles_per_seg);
    const int ox0 = blockIdx.x * TILE;
    const int Hp = H >> 1;
    const long long base = (long long)blockIdx.z * H * H;

    // ---- per-thread staging slots (fixed): slot s = tid + 256*t
    int rHS[4], rS[4], xS[4];
    #pragma unroll
    for (int t4 = 0; t4 < 4; ++t4) {
        const int s = tid + 256 * t4;
        if (s < IN_DIM * SCP) {
            const int r = s / SCP, cp = s - r * SCP;
            rS[t4] = r; rHS[t4] = r * H; xS[t4] = ox0 + 2 * cp;
        } else {
            rS[t4] = -1; rHS[t4] = 0; xS[t4] = 0;
        }
    }

    // load helper: returns (P0,Q0,P1,Q1) for slot t4 at tile row-offset ybase
    auto load_slot = [&](int t4, int ybase) -> float4 {
        float2 a = make_float2(0.f, 0.f), b = make_float2(0.f, 0.f);
        if (rS[t4] >= 0) {
            const int y = ybase + rS[t4], x = xS[t4];
            if (y < H && x < H) {
                const long long idx = base + (long long)ybase * H + rHS[t4] + x;
                a = *(const float2*)(src1 + idx);
                b = *(const float2*)(src2 + idx);
            }
        }
        if (pq_input)
            return make_float4(a.x, b.x, a.y, b.y);                    // already P,Q
        return make_float4(a.x + b.x, a.x - b.x, a.y + b.y, a.y - b.y); // form P,Q
    };

    float4 pref[4];
    // ---- prologue: load + stage first tile
    {
        #pragma unroll
        for (int t4 = 0; t4 < 4; ++t4) pref[t4] = load_slot(t4, tstart * TILE);
        #pragma unroll
        for (int t4 = 0; t4 < 4; ++t4)
            if (rS[t4] >= 0) *(float4*)&smem[(tid + 256 * t4) * 4] = pref[t4];
    }
    __syncthreads();

    float ssim_acc = 0.f, cs_acc = 0.f;

    for (int tt = tstart; tt < tend; ++tt) {
        const int ty0 = tt * TILE;
        const bool more = (tt + 1 < tend);

        // ---- phase A: prefetch next tile into regs
        if (more) {
            #pragma unroll
            for (int t4 = 0; t4 < 4; ++t4) pref[t4] = load_slot(t4, ty0 + TILE);
        }

        // ---- phase A: fused 2x2 avg pool of (P,Q) (pool linearity)
        if (pool1 != nullptr) {
            const int pr = tid >> 4, pc = tid & 15;
            const int py = (ty0 >> 1) + pr, px = (ox0 >> 1) + pc;
            if (py < Hp && px < Hp) {
                const float4 v0 = *(const float4*)&smem[(2 * pr * SCP + pc) * 4];
                const float4 v1 = *(const float4*)&smem[((2 * pr + 1) * SCP + pc) * 4];
                const long long ob = (long long)blockIdx.z * Hp * Hp + (long long)py * Hp + px;
                pool1[ob] = 0.25f * (v0.x + v0.z + v1.x + v1.z);   // pooled P
                pool2[ob] = 0.25f * (v0.y + v0.w + v1.y + v1.w);   // pooled Q
            }
        }

        // ---- phase A: h-pass, 672 (row, colpair) positions -> registers
        vf2 hpqa[3], hsqa[3], hpqb[3], hsqb[3];
        #pragma unroll
        for (int t = 0; t < 3; ++t) {
            const int p = tid + 256 * t;
            if (p < IN_DIM * 16) {
                const int r = p >> 4, m = p & 15;
                vf2 Apq = {0.f, 0.f}, Asq = {0.f, 0.f};
                vf2 Bpq = {0.f, 0.f}, Bsq = {0.f, 0.f};
                #pragma unroll
                for (int jj = 0; jj < 6; ++jj) {
                    const float4 v = *(const float4*)&smem[(r * SCP + m + jj) * 4];
                    const vf2 lo = {v.x, v.y};          // (P_even, Q_even)
                    const vf2 hi = {v.z, v.w};          // (P_odd,  Q_odd)
                    const vf2 losq = pk_mul(lo, lo);    // (P^2, Q^2)
                    const vf2 hisq = pk_mul(hi, hi);
                    // even value j = 2jj: col a weight g[j]; col b weight g[j-1]
                    Apq = pk_fma(wg[2 * jj], lo, Apq);
                    Asq = pk_fma(wg[2 * jj], losq, Asq);
                    if (jj >= 1) {
                        Bpq = pk_fma(wg[2 * jj - 1], lo, Bpq);
                        Bsq = pk_fma(wg[2 * jj - 1], losq, Bsq);
                    }
                    // odd value j = 2jj+1: col a weight g[j] (jj<=4); col b weight g[2jj]
                    if (jj <= 4) {
                        Apq = pk_fma(wg[2 * jj + 1], hi, Apq);
                        Asq = pk_fma(wg[2 * jj + 1], hisq, Asq);
                    }
                    Bpq = pk_fma(wg[2 * jj], hi, Bpq);
                    Bsq = pk_fma(wg[2 * jj], hisq, Bsq);
                }
                hpqa[t] = Apq; hsqa[t] = Asq;
                hpqb[t] = Bpq; hsqb[t] = Bsq;
            }
        }
        __syncthreads();   // staging reads done; h-LDS reads (prev C) done

        // ---- phase B: h-write + stage next tile
        #pragma unroll
        for (int t = 0; t < 3; ++t) {
            const int p = tid + 256 * t;
            if (p < IN_DIM * 16) {
                const int r = p >> 4, m = p & 15;
                const int bpq = HPQ_BASE + m * S12 + r * 4;
                *(vf2*)&smem[bpq]     = hpqa[t];
                *(vf2*)&smem[bpq + 2] = hpqb[t];
                const int bsq = HSQ_BASE + m * S12 + r * 4;
                *(vf2*)&smem[bsq]     = hsqa[t];
                *(vf2*)&smem[bsq + 2] = hsqb[t];
            }
        }
        if (more) {
            #pragma unroll
            for (int t4 = 0; t4 < 4; ++t4)
                if (rS[t4] >= 0) *(float4*)&smem[(tid + 256 * t4) * 4] = pref[t4];
        }
        __syncthreads();

        // ---- phase C: v-pass (pk accumulators) + SSIM
        const int tx = tid & 31, rg = tid >> 5;
        const int r0 = rg * 4;
        const int m = tx >> 1, par = tx & 1;
        const int bpq = HPQ_BASE + m * S12 + par * 2;
        const int bsq = HSQ_BASE + m * S12 + par * 2;

        vf2 accPQ[4], accSQ[4];
        #pragma unroll
        for (int o = 0; o < 4; ++o) {
            accPQ[o] = (vf2){0.f, 0.f};
            accSQ[o] = (vf2){0.f, 0.f};
        }
        #pragma unroll
        for (int i = 0; i < 14; ++i) {
            const vf2 ppq = *(const vf2*)&smem[bpq + (r0 + i) * 4];
            const vf2 psq = *(const vf2*)&smem[bsq + (r0 + i) * 4];
            #pragma unroll
            for (int o = 0; o < 4; ++o) {
                const int k = i - o;
                if (k >= 0 && k <= 10) {
                    accPQ[o] = pk_fma(wg[k], ppq, accPQ[o]);
                    accSQ[o] = pk_fma(wg[k], psq, accSQ[o]);
                }
            }
        }

        const float C1 = 4.0e-4f;   // (0.01*2)^2
        const float C2 = 3.6e-3f;   // (0.03*2)^2
        const int ox = ox0 + tx;
        #pragma unroll
        for (int o = 0; o < 4; ++o) {
            const int oy = ty0 + r0 + o;
            if (oy < Hout && ox < Hout) {
                const vf2 musq = pk_mul(accPQ[o], accPQ[o]);   // (cP^2, cQ^2)
                const float sP = accSQ[o].x - musq.x;
                const float sQ = accSQ[o].y - musq.y;
                const float v1 = 0.5f * (sP - sQ) + C2;        // 2*s12 + C2
                const float v2 = 0.5f * (sP + sQ) + C2;        // s1+s2 + C2
                const float num1 = 0.5f * (musq.x - musq.y) + C1; // 2*mu1*mu2 + C1
                const float den1 = 0.5f * (musq.x + musq.y) + C1; // mu1^2+mu2^2 + C1
                cs_acc += v1 * __builtin_amdgcn_rcpf(v2);
                ssim_acc += num1 * v1 * __builtin_amdgcn_rcpf(den1 * v2);
            }
        }
        // no barrier: next phase A reads staging (already holds tile tt+1);
        // h-LDS rewritten only after the next iteration's first barrier.
    }

    // ---- block reduction + single pair of f64 atomics
    #pragma unroll
    for (int off = 32; off > 0; off >>= 1) {
        ssim_acc += __shfl_down(ssim_acc, off);
        cs_acc   += __shfl_down(cs_acc, off);
    }
    const int wave = tid >> 6;
    if ((tid & 63) == 0) { wred[wave][0] = ssim_acc; wred[wave][1] = cs_acc; }
    __syncthreads();
    if (tid == 0) {
        const float s = wred[0][0] + wred[1][0] + wred[2][0] + wred[3][0];
        const float c = wred[0][1] + wred[1][1] + wred[2][1] + wred[3][1];
        atomicAdd(&sums[level],     (double)s);
        atomicAdd(&sums[5 + level], (double)c);
    }
}

// -------------------- final combine --------------------
__global__ void msssim_final_kernel(const double* __restrict__ sums,
                                    float* __restrict__ out)
{
    if (threadIdx.x == 0 && blockIdx.x == 0) {
        const double W[5] = {0.0448, 0.2856, 0.3001, 0.2363, 0.1333};
        const int Houts[5] = {502, 246, 118, 54, 22};
        double mssim[5], mcs[5];
        for (int l = 0; l < 5; ++l) {
            const double cnt = 48.0 * (double)Houts[l] * (double)Houts[l];
            mssim[l] = (sums[l]     / cnt + 1.0) * 0.5;
            mcs[l]   = (sums[5 + l] / cnt + 1.0) * 0.5;
        }
        const double p2 = pow(mssim[4], W[4]);
        double prod = 1.0;
        for (int l = 0; l < 4; ++l) prod *= pow(mcs[l], W[l]) * p2;
        out[0] = (float)(1.0 - prod);
    }
}

// -------------------- launch --------------------
extern "C" void kernel_launch(void* const* d_in, const int* in_sizes, int n_in,
                              void* d_out, int out_size, void* d_ws, size_t ws_size,
                              hipStream_t stream)
{
    const float* img1 = (const float*)d_in[0];
    const float* img2 = (const float*)d_in[1];
    float* out = (float*)d_out;
    (void)in_sizes; (void)n_in; (void)out_size; (void)ws_size;

    char* ws = (char*)d_ws;
    double* sums = (double*)ws;                      // 10 doubles
    float* X1 = (float*)(ws + 256);                  // 3,145,728 floats (P planes)
    float* X2 = X1 + 3145728;                        // (Q planes)
    float* Y1 = X2 + 3145728;                        // 786,432 floats
    float* Y2 = Y1 + 786432;

    hipMemsetAsync(sums, 0, 10 * sizeof(double), stream);

    // segs: L0 16x1, L1 8x2, L2 4x4, L3 2x2, L4 1x1 (blocks >= ~768 where possible)
    auto launch_level = [&](const float* a, const float* b, int H, int level,
                            int segs, int pq, float* pa, float* pb) {
        const int Hout = H - HALO;
        const int strips = (Hout + TILE - 1) / TILE;
        const int ntiles = (Hout + TILE - 1) / TILE;
        const int tps = (ntiles + segs - 1) / segs;
        dim3 grid(strips, segs, 48);
        hipLaunchKernelGGL(msssim_level_kernel, grid, dim3(256), 0, stream,
                           a, b, H, level, tps, pq, sums, pa, pb);
    };

    launch_level(img1, img2, 512, 0, 1, 0, X1, X2);      // level 0 -> P,Q (256)
    launch_level(X1, X2, 256, 1, 2, 1, Y1, Y2);          // level 1 -> (128)
    launch_level(Y1, Y2, 128, 2, 4, 1, X1, X2);          // level 2 -> (64)
    launch_level(X1, X2, 64, 3, 2, 1, Y1, Y2);           // level 3 -> (32)
    launch_level(Y1, Y2, 32, 4, 1, 1, nullptr, nullptr); // level 4

    hipLaunchKernelGGL(msssim_final_kernel, dim3(1), dim3(64), 0, stream, sums, out);
}